// Round 5
// baseline (238.826 us; speedup 1.0000x reference)
//
#include <hip/hip_runtime.h>
#include <stdint.h>

#define N_V   4096
#define T_PER 4
#define NT    16384
#define D_K   256
#define SCALE 10.0f   // 1/temperature
#define LOG2E 1.44269504088896340736f
#define LN2   0.69314718055994530942f

typedef __bf16 bf16x8 __attribute__((ext_vector_type(8)));
typedef float  f32x4  __attribute__((ext_vector_type(4)));

__device__ __forceinline__ unsigned short f2bf(float f) {
  uint32_t u = __float_as_uint(f);
  u = (u + 0x7fffu + ((u >> 16) & 1u)) >> 16;   // RNE
  return (unsigned short)u;
}

// ---------------- A1: fp32 -> bf16. A carries SCALE*LOG2E so GEMM scores come out in
// log2 domain (exp -> single v_exp_f32, log -> v_log_f32; counts unaffected: monotone) ----
__global__ void k_convert(const float* __restrict__ v, const float* __restrict__ t,
                          unsigned short* __restrict__ Abf, unsigned short* __restrict__ Bbf) {
  int idx = blockIdx.x * blockDim.x + threadIdx.x;
  const int NV4 = N_V * D_K / 4;
  const float AS = SCALE * LOG2E;
  if (idx < NV4) {
    float4 x = ((const float4*)v)[idx];
    ushort4 o;
    o.x = f2bf(x.x * AS); o.y = f2bf(x.y * AS);
    o.z = f2bf(x.z * AS); o.w = f2bf(x.w * AS);
    ((ushort4*)Abf)[idx] = o;
  } else {
    int j = idx - NV4;
    float4 x = ((const float4*)t)[j];
    ushort4 o;
    o.x = f2bf(x.x); o.y = f2bf(x.y); o.z = f2bf(x.z); o.w = f2bf(x.w);
    ((ushort4*)Bbf)[j] = o;
  }
}

// ---------------- A2: diagonal dots (fp32-exact) -> thresholds (log2 domain) + nominator
// (natural log); zero d_out for the later atomicAdd ----------------------------------------
__global__ void k_thr(const float* __restrict__ v, const float* __restrict__ t,
                      float* __restrict__ thr, float* __restrict__ nom,
                      float* __restrict__ out) {
  int i = blockIdx.x;
  int l = threadIdx.x;                       // one wave per video
  if (i == 0 && l < 5) out[l] = 0.0f;
  float4 a = ((const float4*)(v + (size_t)i * D_K))[l];
  float tv[T_PER];
#pragma unroll
  for (int tt = 0; tt < T_PER; ++tt) {
    float4 b = ((const float4*)(t + (size_t)(i * T_PER + tt) * D_K))[l];
    float d = a.x * b.x + a.y * b.y + a.z * b.z + a.w * b.w;
#pragma unroll
    for (int s = 1; s < 64; s <<= 1) d += __shfl_xor(d, s);
    tv[tt] = d * SCALE;                      // natural-domain score
  }
  if (l == 0) {
    // thresholds in log2 domain to match the GEMM scores
    ((float4*)thr)[i] = make_float4(tv[0] * LOG2E, tv[1] * LOG2E,
                                    tv[2] * LOG2E, tv[3] * LOG2E);
    float m = fmaxf(fmaxf(tv[0], tv[1]), fmaxf(tv[2], tv[3]));
    float e = __expf(tv[0] - m) + __expf(tv[1] - m) + __expf(tv[2] - m) + __expf(tv[3] - m);
    nom[i] = m + __logf(e);                  // natural log
  }
}

// ---------------- B: barrier-free direct-from-global MFMA GEMM + LSE/rank epilogue ---------
// Fragment layout for mfma_f32_16x16x32_bf16 (A and B operands): lane (nl,quad) holds
// M[row=nl][k=quad*8 .. +8) — a contiguous 16 B slice of the row-major bf16 matrix.
// So fragments load straight from global (L2-hot: A shared by 16 ct-blocks/XCD, B by 32
// rt-blocks on its home XCD). No LDS staging, no K-loop barriers, no vmcnt(0) drains.
__global__ __launch_bounds__(256, 3) void k_gemm(
    const unsigned short* __restrict__ Abf, const unsigned short* __restrict__ Bbf,
    const float* __restrict__ thr,
    float* __restrict__ pmax, float* __restrict__ psum, uint32_t* __restrict__ pcnt,
    float* __restrict__ cmax, float* __restrict__ csum) {
  __shared__ float4   thrS[128];
  __shared__ float    rowM[2][128];   // [col-half][row] per-row maxes (underflow safety)
  __shared__ float    rowE[2][128];   // [col-half][row] exp-sums rel. to own row max
  __shared__ uint32_t rowC[2][128];   // [col-half][row] packed counts
  __shared__ float    colM[2][128];   // [row-half][col] per-col maxes
  __shared__ float    colE[2][128];   // [row-half][col] exp-sums rel. to own col max

  const int ct = blockIdx.x, rt = blockIdx.y;
  const int row0 = rt * 128, col0 = ct * 128;
  const int tid = threadIdx.x;
  const int l = tid & 63, w = tid >> 6;
  const int quad = l >> 4, nl = l & 15;
  const int wr0 = (w >> 1) * 64, wc0 = (w & 1) * 64;

  if (tid < 128) thrS[tid] = ((const float4*)thr)[row0 + tid];
  __syncthreads();

  // per-lane fragment base pointers (constant over the K loop; chunks via imm offsets)
  const unsigned short* pA[4];
  const unsigned short* pB[4];
#pragma unroll
  for (int i = 0; i < 4; ++i) {
    pA[i] = Abf + (size_t)(row0 + wr0 + i * 16 + nl) * D_K + quad * 8;
    pB[i] = Bbf + (size_t)(col0 + wc0 + i * 16 + nl) * D_K + quad * 8;
  }

  f32x4 acc[4][4];
#pragma unroll
  for (int i = 0; i < 4; ++i)
#pragma unroll
    for (int j = 0; j < 4; ++j) acc[i][j] = {0.f, 0.f, 0.f, 0.f};

  // K loop: 8 chunks of 32, 1-deep register prefetch, zero barriers
  bf16x8 a_[2][4], b_[2][4];
#pragma unroll
  for (int i = 0; i < 4; ++i) {
    a_[0][i] = *(const bf16x8*)(pA[i]);
    b_[0][i] = *(const bf16x8*)(pB[i]);
  }
#pragma unroll
  for (int c = 0; c < 8; ++c) {
    const int cur = c & 1, nxt = cur ^ 1;
    if (c < 7) {
#pragma unroll
      for (int i = 0; i < 4; ++i) {
        a_[nxt][i] = *(const bf16x8*)(pA[i] + (c + 1) * 32);
        b_[nxt][i] = *(const bf16x8*)(pB[i] + (c + 1) * 32);
      }
    }
#pragma unroll
    for (int i = 0; i < 4; ++i)
#pragma unroll
      for (int j = 0; j < 4; ++j)
        acc[i][j] = __builtin_amdgcn_mfma_f32_16x16x32_bf16(a_[cur][i], b_[cur][j],
                                                            acc[i][j], 0, 0, 0);
  }

  // ================= epilogue (scores in log2 domain) =================
  // C/D layout: col = nl, row = quad*4 + reg.  Per-row/per-col maxes are mandatory
  // (sigma ~230 in log2 units; a shared max underflows exp2 to 0 -> log(0) downstream).

  // rank counts vs thresholds, packed 4x8-bit per (row,lane)
  uint32_t cnt[4][4];
#pragma unroll
  for (int i = 0; i < 4; ++i)
#pragma unroll
    for (int r = 0; r < 4; ++r) {
      float4 th = thrS[wr0 + i * 16 + quad * 4 + r];
      uint32_t c = 0;
#pragma unroll
      for (int j = 0; j < 4; ++j) {
        float s = acc[i][j][r];
        c += (uint32_t)(s > th.x);
        c += (uint32_t)(s > th.y) << 8;
        c += (uint32_t)(s > th.z) << 16;
        c += (uint32_t)(s > th.w) << 24;
      }
      cnt[i][r] = c;
    }

  // row partials: per-row max (guarantees e >= 1), exp2-sum, count
#pragma unroll
  for (int i = 0; i < 4; ++i)
#pragma unroll
    for (int r = 0; r < 4; ++r) {
      float m = fmaxf(fmaxf(acc[i][0][r], acc[i][1][r]), fmaxf(acc[i][2][r], acc[i][3][r]));
#pragma unroll
      for (int d = 1; d < 16; d <<= 1) m = fmaxf(m, __shfl_xor(m, d));
      float e = exp2f(acc[i][0][r] - m) + exp2f(acc[i][1][r] - m)
              + exp2f(acc[i][2][r] - m) + exp2f(acc[i][3][r] - m);
      uint32_t c = cnt[i][r];
#pragma unroll
      for (int d = 1; d < 16; d <<= 1) { e += __shfl_xor(e, d); c += __shfl_xor(c, d); }
      if (nl == 0) {
        int row = wr0 + i * 16 + quad * 4 + r;
        rowM[w & 1][row] = m; rowE[w & 1][row] = e; rowC[w & 1][row] = c;
      }
    }

  // col partials: per-col max, exp2-sum
#pragma unroll
  for (int j = 0; j < 4; ++j) {
    float m = -3.0e38f;
#pragma unroll
    for (int i = 0; i < 4; ++i)
#pragma unroll
      for (int r = 0; r < 4; ++r) m = fmaxf(m, acc[i][j][r]);
    m = fmaxf(m, __shfl_xor(m, 16));
    m = fmaxf(m, __shfl_xor(m, 32));
    float e = 0.f;
#pragma unroll
    for (int i = 0; i < 4; ++i)
#pragma unroll
      for (int r = 0; r < 4; ++r) e += exp2f(acc[i][j][r] - m);
    e += __shfl_xor(e, 16);
    e += __shfl_xor(e, 32);
    if (quad == 0) {
      int col = wc0 + j * 16 + nl;
      colM[w >> 1][col] = m; colE[w >> 1][col] = e;
    }
  }
  __syncthreads();

  // combine the two halves (online-LSE merge), coalesced [part][global-idx] writes
  if (tid < 128) {
    float M0 = rowM[0][tid], M1 = rowM[1][tid];
    float Mx = fmaxf(M0, M1);
    float Sx = rowE[0][tid] * exp2f(M0 - Mx) + rowE[1][tid] * exp2f(M1 - Mx);
    uint32_t C = rowC[0][tid] + rowC[1][tid];
    size_t gi = (size_t)ct * N_V + row0 + tid;
    pmax[gi] = Mx; psum[gi] = Sx; pcnt[gi] = C;
  } else {
    int c = tid - 128;
    float M0 = colM[0][c], M1 = colM[1][c];
    float Mx = fmaxf(M0, M1);
    float Sx = colE[0][c] * exp2f(M0 - Mx) + colE[1][c] * exp2f(M1 - Mx);
    size_t gi = (size_t)rt * NT + col0 + c;
    cmax[gi] = Mx; csum[gi] = Sx;
  }
}

// ---------------- C: reduce 128 row-partials per row (coalesced, lane-owns-row) ------------
__global__ void k_rowred(const float* __restrict__ pmax, const float* __restrict__ psum,
                         const uint32_t* __restrict__ pcnt,
                         float* __restrict__ rowm, float* __restrict__ rows_,
                         uint4* __restrict__ rcnt) {
  __shared__ float Lm[4][64], Ls[4][64];
  __shared__ uint4 Lc[4][64];
  int tid = threadIdx.x, l = tid & 63, w = tid >> 6;
  int row = blockIdx.x * 64 + l;
  float M = -3.0e38f, S = 0.f;
  uint32_t c0 = 0, c1 = 0, c2 = 0, c3 = 0;
  for (int k = 0; k < 32; ++k) {
    size_t idx = (size_t)(w * 32 + k) * N_V + row;
    float m = pmax[idx], s = psum[idx];
    uint32_t cc = pcnt[idx];
    float nM = fmaxf(M, m);
    S = S * exp2f(M - nM) + s * exp2f(m - nM);
    M = nM;
    c0 += cc & 0xffu; c1 += (cc >> 8) & 0xffu;
    c2 += (cc >> 16) & 0xffu; c3 += cc >> 24;
  }
  Lm[w][l] = M; Ls[w][l] = S; Lc[w][l] = make_uint4(c0, c1, c2, c3);
  __syncthreads();
  if (tid < 64) {
    float Mx = Lm[0][tid], Sx = Ls[0][tid];
    uint4 C = Lc[0][tid];
#pragma unroll
    for (int ww = 1; ww < 4; ++ww) {
      float m = Lm[ww][tid], s = Ls[ww][tid];
      float nM = fmaxf(Mx, m);
      Sx = Sx * exp2f(Mx - nM) + s * exp2f(m - nM);
      Mx = nM;
      uint4 cc = Lc[ww][tid];
      C.x += cc.x; C.y += cc.y; C.z += cc.z; C.w += cc.w;
    }
    int r = blockIdx.x * 64 + tid;
    rowm[r] = Mx; rows_[r] = Sx; rcnt[r] = C;
  }
}

// ---------------- D: reduce 32 col-partials per column (coalesced) -------------------------
__global__ void k_colred(const float* __restrict__ cmax, const float* __restrict__ csum,
                         float* __restrict__ colm, float* __restrict__ cols) {
  __shared__ float Cm[2][128], Cs[2][128];
  int tid = threadIdx.x, c = tid & 127, h = tid >> 7;
  int col = blockIdx.x * 128 + c;
  float M = -3.0e38f, S = 0.f;
  for (int k = 0; k < 16; ++k) {
    size_t idx = (size_t)(h * 16 + k) * NT + col;
    float m = cmax[idx], s = csum[idx];
    float nM = fmaxf(M, m);
    S = S * exp2f(M - nM) + s * exp2f(m - nM);
    M = nM;
  }
  Cm[h][c] = M; Cs[h][c] = S;
  __syncthreads();
  if (tid < 128) {
    float M0 = Cm[0][tid], S0 = Cs[0][tid];
    float M1 = Cm[1][tid], S1 = Cs[1][tid];
    float Mx = fmaxf(M0, M1);
    float Sx = S0 * exp2f(M0 - Mx) + S1 * exp2f(M1 - Mx);
    int cg = blockIdx.x * 128 + tid;
    colm[cg] = Mx; cols[cg] = Sx;
  }
}

// ---------------- E: combine per row, loss + metrics, atomic means -------------------------
__global__ void k_final(const float* __restrict__ rowm, const float* __restrict__ rows_,
                        const uint4* __restrict__ rcnt, const float* __restrict__ nom,
                        const float* __restrict__ colm, const float* __restrict__ cols,
                        float* __restrict__ out) {
  int row = blockIdx.x * 256 + threadIdx.x;
  float M = rowm[row], S = rows_[row];
  float cm0 = colm[row * 4 + 0], cm1 = colm[row * 4 + 1];
  float cm2 = colm[row * 4 + 2], cm3 = colm[row * 4 + 3];
  float cs0 = cols[row * 4 + 0], cs1 = cols[row * 4 + 1];
  float cs2 = cols[row * 4 + 2], cs3 = cols[row * 4 + 3];
  float Mp = fmaxf(M, fmaxf(fmaxf(cm0, cm1), fmaxf(cm2, cm3)));
  float tot = S * exp2f(M - Mp)
            + cs0 * exp2f(cm0 - Mp) + cs1 * exp2f(cm1 - Mp)
            + cs2 * exp2f(cm2 - Mp) + cs3 * exp2f(cm3 - Mp);
  // scores were in log2 domain: natural-log LSE = LN2 * (Mp + log2(tot))
  float ll = LN2 * (Mp + log2f(tot)) - nom[row];
  uint4 c = rcnt[row];
  float ar  = (float)(c.x + c.y + c.z + c.w) * 0.25f;
  float r1  = (float)((c.x < 1u) + (c.y < 1u) + (c.z < 1u) + (c.w < 1u)) * 0.25f;
  float r5  = (float)((c.x < 5u) + (c.y < 5u) + (c.z < 5u) + (c.w < 5u)) * 0.25f;
  float r10 = (float)((c.x < 10u) + (c.y < 10u) + (c.z < 10u) + (c.w < 10u)) * 0.25f;
  float vals[5] = {ll, r1, r5, r10, ar};
  int l = threadIdx.x & 63;
#pragma unroll
  for (int k = 0; k < 5; ++k) {
    float v = vals[k];
#pragma unroll
    for (int d = 1; d < 64; d <<= 1) v += __shfl_xor(v, d);
    if (l == 0) atomicAdd(&out[k], v * (1.0f / N_V));
  }
}

extern "C" void kernel_launch(void* const* d_in, const int* in_sizes, int n_in,
                              void* d_out, int out_size, void* d_ws, size_t ws_size,
                              hipStream_t stream) {
  const float* v = (const float*)d_in[0];
  const float* t = (const float*)d_in[1];
  char* p = (char*)d_ws;
  unsigned short* Abf = (unsigned short*)p; p += (size_t)N_V * D_K * 2;
  unsigned short* Bbf = (unsigned short*)p; p += (size_t)NT * D_K * 2;
  float* thr  = (float*)p;    p += (size_t)N_V * 4 * 4;
  float* nom  = (float*)p;    p += (size_t)N_V * 4;
  float* pmax = (float*)p;    p += (size_t)128 * N_V * 4;
  float* psum = (float*)p;    p += (size_t)128 * N_V * 4;
  uint32_t* pcnt = (uint32_t*)p; p += (size_t)128 * N_V * 4;
  float* cmaxp = (float*)p;   p += (size_t)32 * NT * 4;
  float* csump = (float*)p;   p += (size_t)32 * NT * 4;
  float* rowm = (float*)p;    p += (size_t)N_V * 4;
  float* rows_ = (float*)p;   p += (size_t)N_V * 4;
  uint4* rcnt = (uint4*)p;    p += (size_t)N_V * 16;
  float* colm = (float*)p;    p += (size_t)NT * 4;
  float* cols = (float*)p;    p += (size_t)NT * 4;
  // total ws: ~20.5 MB

  k_convert<<<(N_V * D_K / 4 + NT * D_K / 4) / 256, 256, 0, stream>>>(v, t, Abf, Bbf);
  k_thr<<<N_V, 64, 0, stream>>>(v, t, thr, nom, (float*)d_out);
  dim3 g(NT / 128, N_V / 128);
  k_gemm<<<g, 256, 0, stream>>>(Abf, Bbf, thr, pmax, psum, pcnt, cmaxp, csump);
  k_rowred<<<N_V / 64, 256, 0, stream>>>(pmax, psum, pcnt, rowm, rows_, rcnt);
  k_colred<<<NT / 128, 256, 0, stream>>>(cmaxp, csump, colm, cols);
  k_final<<<N_V / 256, 256, 0, stream>>>(rowm, rows_, rcnt, nom, colm, cols, (float*)d_out);
}

// Round 6
// 204.794 us; speedup vs baseline: 1.1662x; 1.1662x over previous
//
#include <hip/hip_runtime.h>
#include <stdint.h>

#define N_V   4096
#define T_PER 4
#define NT    16384
#define D_K   256
#define SCALE 10.0f   // 1/temperature
#define LOG2E 1.44269504088896340736f
#define LN2   0.69314718055994530942f

typedef __bf16 bf16x8 __attribute__((ext_vector_type(8)));
typedef float  f32x4  __attribute__((ext_vector_type(4)));

__device__ __forceinline__ unsigned short f2bf(float f) {
  uint32_t u = __float_as_uint(f);
  u = (u + 0x7fffu + ((u >> 16) & 1u)) >> 16;   // RNE
  return (unsigned short)u;
}

// ---------------- A: fused convert + diagonal dots (reads v,t exactly once) ---------------
// A-side bf16 carries SCALE*LOG2E so GEMM scores come out in log2 domain.
// Thresholds emitted in log2 domain; nominator in natural log. Zeroes d_out for atomics.
__global__ void k_prep(const float* __restrict__ v, const float* __restrict__ t,
                       unsigned short* __restrict__ Abf, unsigned short* __restrict__ Bbf,
                       float* __restrict__ thr, float* __restrict__ nom,
                       float* __restrict__ out) {
  const int tid = threadIdx.x, l = tid & 63, w = tid >> 6;
  const int i = blockIdx.x * 4 + w;            // one wave per video
  if (blockIdx.x == 0 && tid < 5) out[tid] = 0.0f;
  const float AS = SCALE * LOG2E;

  float4 a = ((const float4*)(v + (size_t)i * D_K))[l];
  ushort4 oa;
  oa.x = f2bf(a.x * AS); oa.y = f2bf(a.y * AS);
  oa.z = f2bf(a.z * AS); oa.w = f2bf(a.w * AS);
  ((ushort4*)(Abf + (size_t)i * D_K))[l] = oa;

  float tv[T_PER];
#pragma unroll
  for (int tt = 0; tt < T_PER; ++tt) {
    float4 b = ((const float4*)(t + (size_t)(i * T_PER + tt) * D_K))[l];
    ushort4 ob;
    ob.x = f2bf(b.x); ob.y = f2bf(b.y); ob.z = f2bf(b.z); ob.w = f2bf(b.w);
    ((ushort4*)(Bbf + (size_t)(i * T_PER + tt) * D_K))[l] = ob;
    float d = a.x * b.x + a.y * b.y + a.z * b.z + a.w * b.w;
#pragma unroll
    for (int s = 1; s < 64; s <<= 1) d += __shfl_xor(d, s);
    tv[tt] = d * SCALE;                        // natural-domain score
  }
  if (l == 0) {
    ((float4*)thr)[i] = make_float4(tv[0] * LOG2E, tv[1] * LOG2E,
                                    tv[2] * LOG2E, tv[3] * LOG2E);
    float m = fmaxf(fmaxf(tv[0], tv[1]), fmaxf(tv[2], tv[3]));
    float e = __expf(tv[0] - m) + __expf(tv[1] - m) + __expf(tv[2] - m) + __expf(tv[3] - m);
    nom[i] = m + __logf(e);
  }
}

// ---------------- B: double-buffered MFMA GEMM + LSE/rank-count epilogue -------------------
__device__ __forceinline__ void gld16(const void* g, void* l) {
  __builtin_amdgcn_global_load_lds((const __attribute__((address_space(1))) void*)g,
                                   (__attribute__((address_space(3))) void*)l,
                                   16, 0, 0);
}

// K-loop pipelining: loads for chunk n+1 are issued immediately AFTER the barrier that
// publishes chunk n. The compiler's vmcnt(0)-before-barrier then waits only on loads that
// had a full MFMA phase in flight — only the first load is ever exposed. (At K=256 there
// are just 4 iterations; the r4 single-buffer structure drained cold loads 4x per block.)
__global__ __launch_bounds__(256) void k_gemm(
    const unsigned short* __restrict__ Abf, const unsigned short* __restrict__ Bbf,
    const float* __restrict__ thr,
    float* __restrict__ pmax, float* __restrict__ psum, uint32_t* __restrict__ pcnt,
    float* __restrict__ cmax, float* __restrict__ csum) {
  __shared__ __align__(16) unsigned short As[2][128 * 64];
  __shared__ __align__(16) unsigned short Bs[2][128 * 64];
  __shared__ float4   thrS[128];
  __shared__ float    rowM[2][128];   // [col-half][row] per-row maxes (underflow safety)
  __shared__ float    rowE[2][128];   // [col-half][row] exp-sums rel. to own row max
  __shared__ uint32_t rowC[2][128];   // [col-half][row] packed counts
  __shared__ float    colM[2][128];   // [row-half][col] per-col maxes
  __shared__ float    colE[2][128];   // [row-half][col] exp-sums rel. to own col max

  const int ct = blockIdx.x, rt = blockIdx.y;
  const int row0 = rt * 128, col0 = ct * 128;
  const int tid = threadIdx.x;
  const int l = tid & 63, w = tid >> 6;
  const int quad = l >> 4, nl = l & 15;
  const int wr0 = (w >> 1) * 64, wc0 = (w & 1) * 64;

  if (tid < 128) thrS[tid] = ((const float4*)thr)[row0 + tid];

  f32x4 acc[4][4];
#pragma unroll
  for (int i = 0; i < 4; ++i)
#pragma unroll
    for (int j = 0; j < 4; ++j) acc[i][j] = {0.f, 0.f, 0.f, 0.f};

  const int lr = l >> 3;            // row within 8-row group
  const int lc = (l & 7) ^ lr;      // swizzled global chunk index

  auto stage = [&](int buf, int k0) {
#pragma unroll
    for (int it = 0; it < 4; ++it) {
      int g = w * 4 + it;           // 16 groups of 8 rows
      const unsigned short* ga = Abf + (size_t)(row0 + g * 8 + lr) * D_K + k0 + lc * 8;
      gld16(ga, (char*)As[buf] + g * 1024);
      const unsigned short* gb = Bbf + (size_t)(col0 + g * 8 + lr) * D_K + k0 + lc * 8;
      gld16(gb, (char*)Bs[buf] + g * 1024);
    }
  };
  auto compute = [&](int buf) {
#pragma unroll
    for (int kk = 0; kk < 64; kk += 32) {
      const int cb = (kk >> 3) + quad;
      bf16x8 af[4], bv[4];
#pragma unroll
      for (int i = 0; i < 4; ++i) {
        int r = wr0 + i * 16 + nl;
        af[i] = *(const bf16x8*)((const char*)As[buf] + r * 128 + ((cb ^ (r & 7)) << 4));
      }
#pragma unroll
      for (int j = 0; j < 4; ++j) {
        int n = wc0 + j * 16 + nl;
        bv[j] = *(const bf16x8*)((const char*)Bs[buf] + n * 128 + ((cb ^ (n & 7)) << 4));
      }
#pragma unroll
      for (int i = 0; i < 4; ++i)
#pragma unroll
        for (int j = 0; j < 4; ++j)
          acc[i][j] = __builtin_amdgcn_mfma_f32_16x16x32_bf16(af[i], bv[j], acc[i][j], 0, 0, 0);
    }
  };

  stage(0, 0);                       // chunk 0 (cold — only exposed drain)
#pragma unroll
  for (int it = 0; it < 4; ++it) {
    __syncthreads();                 // publishes buffer it&1 (compiler waits vmcnt/lgkm)
    if (it < 3) stage((it + 1) & 1, (it + 1) * 64);   // issue next AFTER the barrier
    compute(it & 1);
  }

  // ================= epilogue (scores in log2 domain) =================
  // C/D layout: col = nl, row = quad*4 + reg.  Per-row/per-col maxes mandatory
  // (sigma ~230 log2 units; shared max underflows exp2 -> log(0) downstream).

  uint32_t cnt[4][4];
#pragma unroll
  for (int i = 0; i < 4; ++i)
#pragma unroll
    for (int r = 0; r < 4; ++r) {
      float4 th = thrS[wr0 + i * 16 + quad * 4 + r];
      uint32_t c = 0;
#pragma unroll
      for (int j = 0; j < 4; ++j) {
        float s = acc[i][j][r];
        c += (uint32_t)(s > th.x);
        c += (uint32_t)(s > th.y) << 8;
        c += (uint32_t)(s > th.z) << 16;
        c += (uint32_t)(s > th.w) << 24;
      }
      cnt[i][r] = c;
    }

  // row partials: per-row max (guarantees e >= 1), exp2-sum, count
#pragma unroll
  for (int i = 0; i < 4; ++i)
#pragma unroll
    for (int r = 0; r < 4; ++r) {
      float m = fmaxf(fmaxf(acc[i][0][r], acc[i][1][r]), fmaxf(acc[i][2][r], acc[i][3][r]));
#pragma unroll
      for (int d = 1; d < 16; d <<= 1) m = fmaxf(m, __shfl_xor(m, d));
      float e = exp2f(acc[i][0][r] - m) + exp2f(acc[i][1][r] - m)
              + exp2f(acc[i][2][r] - m) + exp2f(acc[i][3][r] - m);
      uint32_t c = cnt[i][r];
#pragma unroll
      for (int d = 1; d < 16; d <<= 1) { e += __shfl_xor(e, d); c += __shfl_xor(c, d); }
      if (nl == 0) {
        int row = wr0 + i * 16 + quad * 4 + r;
        rowM[w & 1][row] = m; rowE[w & 1][row] = e; rowC[w & 1][row] = c;
      }
    }

  // col partials: per-col max, exp2-sum
#pragma unroll
  for (int j = 0; j < 4; ++j) {
    float m = -3.0e38f;
#pragma unroll
    for (int i = 0; i < 4; ++i)
#pragma unroll
      for (int r = 0; r < 4; ++r) m = fmaxf(m, acc[i][j][r]);
    m = fmaxf(m, __shfl_xor(m, 16));
    m = fmaxf(m, __shfl_xor(m, 32));
    float e = 0.f;
#pragma unroll
    for (int i = 0; i < 4; ++i)
#pragma unroll
      for (int r = 0; r < 4; ++r) e += exp2f(acc[i][j][r] - m);
    e += __shfl_xor(e, 16);
    e += __shfl_xor(e, 32);
    if (quad == 0) {
      int col = wc0 + j * 16 + nl;
      colM[w >> 1][col] = m; colE[w >> 1][col] = e;
    }
  }
  __syncthreads();

  // combine the two halves (online-LSE merge), coalesced [part][global-idx] writes
  if (tid < 128) {
    float M0 = rowM[0][tid], M1 = rowM[1][tid];
    float Mx = fmaxf(M0, M1);
    float Sx = rowE[0][tid] * exp2f(M0 - Mx) + rowE[1][tid] * exp2f(M1 - Mx);
    uint32_t C = rowC[0][tid] + rowC[1][tid];
    size_t gi = (size_t)ct * N_V + row0 + tid;
    pmax[gi] = Mx; psum[gi] = Sx; pcnt[gi] = C;
  } else {
    int c = tid - 128;
    float M0 = colM[0][c], M1 = colM[1][c];
    float Mx = fmaxf(M0, M1);
    float Sx = colE[0][c] * exp2f(M0 - Mx) + colE[1][c] * exp2f(M1 - Mx);
    size_t gi = (size_t)rt * NT + col0 + c;
    cmax[gi] = Mx; csum[gi] = Sx;
  }
}

// ---------------- C: reduce 128 row-partials per row (coalesced, lane-owns-row) ------------
__global__ void k_rowred(const float* __restrict__ pmax, const float* __restrict__ psum,
                         const uint32_t* __restrict__ pcnt,
                         float* __restrict__ rowm, float* __restrict__ rows_,
                         uint4* __restrict__ rcnt) {
  __shared__ float Lm[4][64], Ls[4][64];
  __shared__ uint4 Lc[4][64];
  int tid = threadIdx.x, l = tid & 63, w = tid >> 6;
  int row = blockIdx.x * 64 + l;
  float M = -3.0e38f, S = 0.f;
  uint32_t c0 = 0, c1 = 0, c2 = 0, c3 = 0;
  for (int k = 0; k < 32; ++k) {
    size_t idx = (size_t)(w * 32 + k) * N_V + row;
    float m = pmax[idx], s = psum[idx];
    uint32_t cc = pcnt[idx];
    float nM = fmaxf(M, m);
    S = S * exp2f(M - nM) + s * exp2f(m - nM);
    M = nM;
    c0 += cc & 0xffu; c1 += (cc >> 8) & 0xffu;
    c2 += (cc >> 16) & 0xffu; c3 += cc >> 24;
  }
  Lm[w][l] = M; Ls[w][l] = S; Lc[w][l] = make_uint4(c0, c1, c2, c3);
  __syncthreads();
  if (tid < 64) {
    float Mx = Lm[0][tid], Sx = Ls[0][tid];
    uint4 C = Lc[0][tid];
#pragma unroll
    for (int ww = 1; ww < 4; ++ww) {
      float m = Lm[ww][tid], s = Ls[ww][tid];
      float nM = fmaxf(Mx, m);
      Sx = Sx * exp2f(Mx - nM) + s * exp2f(m - nM);
      Mx = nM;
      uint4 cc = Lc[ww][tid];
      C.x += cc.x; C.y += cc.y; C.z += cc.z; C.w += cc.w;
    }
    int r = blockIdx.x * 64 + tid;
    rowm[r] = Mx; rows_[r] = Sx; rcnt[r] = C;
  }
}

// ---------------- D: reduce 32 col-partials per column (coalesced) -------------------------
__global__ void k_colred(const float* __restrict__ cmax, const float* __restrict__ csum,
                         float* __restrict__ colm, float* __restrict__ cols) {
  __shared__ float Cm[2][128], Cs[2][128];
  int tid = threadIdx.x, c = tid & 127, h = tid >> 7;
  int col = blockIdx.x * 128 + c;
  float M = -3.0e38f, S = 0.f;
  for (int k = 0; k < 16; ++k) {
    size_t idx = (size_t)(h * 16 + k) * NT + col;
    float m = cmax[idx], s = csum[idx];
    float nM = fmaxf(M, m);
    S = S * exp2f(M - nM) + s * exp2f(m - nM);
    M = nM;
  }
  Cm[h][c] = M; Cs[h][c] = S;
  __syncthreads();
  if (tid < 128) {
    float M0 = Cm[0][tid], S0 = Cs[0][tid];
    float M1 = Cm[1][tid], S1 = Cs[1][tid];
    float Mx = fmaxf(M0, M1);
    float Sx = S0 * exp2f(M0 - Mx) + S1 * exp2f(M1 - Mx);
    int cg = blockIdx.x * 128 + tid;
    colm[cg] = Mx; cols[cg] = Sx;
  }
}

// ---------------- E: combine per row, loss + metrics, atomic means -------------------------
__global__ void k_final(const float* __restrict__ rowm, const float* __restrict__ rows_,
                        const uint4* __restrict__ rcnt, const float* __restrict__ nom,
                        const float* __restrict__ colm, const float* __restrict__ cols,
                        float* __restrict__ out) {
  int row = blockIdx.x * 256 + threadIdx.x;
  float M = rowm[row], S = rows_[row];
  float cm0 = colm[row * 4 + 0], cm1 = colm[row * 4 + 1];
  float cm2 = colm[row * 4 + 2], cm3 = colm[row * 4 + 3];
  float cs0 = cols[row * 4 + 0], cs1 = cols[row * 4 + 1];
  float cs2 = cols[row * 4 + 2], cs3 = cols[row * 4 + 3];
  float Mp = fmaxf(M, fmaxf(fmaxf(cm0, cm1), fmaxf(cm2, cm3)));
  float tot = S * exp2f(M - Mp)
            + cs0 * exp2f(cm0 - Mp) + cs1 * exp2f(cm1 - Mp)
            + cs2 * exp2f(cm2 - Mp) + cs3 * exp2f(cm3 - Mp);
  // scores in log2 domain: natural-log LSE = LN2 * (Mp + log2(tot))
  float ll = LN2 * (Mp + log2f(tot)) - nom[row];
  uint4 c = rcnt[row];
  float ar  = (float)(c.x + c.y + c.z + c.w) * 0.25f;
  float r1  = (float)((c.x < 1u) + (c.y < 1u) + (c.z < 1u) + (c.w < 1u)) * 0.25f;
  float r5  = (float)((c.x < 5u) + (c.y < 5u) + (c.z < 5u) + (c.w < 5u)) * 0.25f;
  float r10 = (float)((c.x < 10u) + (c.y < 10u) + (c.z < 10u) + (c.w < 10u)) * 0.25f;
  float vals[5] = {ll, r1, r5, r10, ar};
  int l = threadIdx.x & 63;
#pragma unroll
  for (int k = 0; k < 5; ++k) {
    float v = vals[k];
#pragma unroll
    for (int d = 1; d < 64; d <<= 1) v += __shfl_xor(v, d);
    if (l == 0) atomicAdd(&out[k], v * (1.0f / N_V));
  }
}

extern "C" void kernel_launch(void* const* d_in, const int* in_sizes, int n_in,
                              void* d_out, int out_size, void* d_ws, size_t ws_size,
                              hipStream_t stream) {
  const float* v = (const float*)d_in[0];
  const float* t = (const float*)d_in[1];
  char* p = (char*)d_ws;
  unsigned short* Abf = (unsigned short*)p; p += (size_t)N_V * D_K * 2;
  unsigned short* Bbf = (unsigned short*)p; p += (size_t)NT * D_K * 2;
  float* thr  = (float*)p;    p += (size_t)N_V * 4 * 4;
  float* nom  = (float*)p;    p += (size_t)N_V * 4;
  float* pmax = (float*)p;    p += (size_t)128 * N_V * 4;
  float* psum = (float*)p;    p += (size_t)128 * N_V * 4;
  uint32_t* pcnt = (uint32_t*)p; p += (size_t)128 * N_V * 4;
  float* cmaxp = (float*)p;   p += (size_t)32 * NT * 4;
  float* csump = (float*)p;   p += (size_t)32 * NT * 4;
  float* rowm = (float*)p;    p += (size_t)N_V * 4;
  float* rows_ = (float*)p;   p += (size_t)N_V * 4;
  uint4* rcnt = (uint4*)p;    p += (size_t)N_V * 16;
  float* colm = (float*)p;    p += (size_t)NT * 4;
  float* cols = (float*)p;    p += (size_t)NT * 4;
  // total ws: ~20.5 MB

  k_prep<<<N_V / 4, 256, 0, stream>>>(v, t, Abf, Bbf, thr, nom, (float*)d_out);
  dim3 g(NT / 128, N_V / 128);
  k_gemm<<<g, 256, 0, stream>>>(Abf, Bbf, thr, pmax, psum, pcnt, cmaxp, csump);
  k_rowred<<<N_V / 64, 256, 0, stream>>>(pmax, psum, pcnt, rowm, rows_, rcnt);
  k_colred<<<NT / 128, 256, 0, stream>>>(cmaxp, csump, colm, cols);
  k_final<<<N_V / 256, 256, 0, stream>>>(rowm, rows_, rcnt, nom, colm, cols, (float*)d_out);
}

// Round 7
// 196.468 us; speedup vs baseline: 1.2156x; 1.0424x over previous
//
#include <hip/hip_runtime.h>
#include <stdint.h>

#define N_V   4096
#define T_PER 4
#define NT    16384
#define D_K   256
#define SCALE 10.0f   // 1/temperature
#define LOG2E 1.44269504088896340736f
#define LN2   0.69314718055994530942f

#if defined(__has_builtin)
#if __has_builtin(__builtin_amdgcn_exp2f)
#define EXP2F(x) __builtin_amdgcn_exp2f(x)
#endif
#endif
#ifndef EXP2F
#define EXP2F(x) exp2f(x)
#endif

typedef __bf16 bf16x8 __attribute__((ext_vector_type(8)));
typedef float  f32x4  __attribute__((ext_vector_type(4)));

__device__ __forceinline__ unsigned short f2bf(float f) {
  uint32_t u = __float_as_uint(f);
  u = (u + 0x7fffu + ((u >> 16) & 1u)) >> 16;   // RNE
  return (unsigned short)u;
}

// ---------------- A: fused convert + diagonal dots (reads v,t exactly once) ---------------
// A-side bf16 carries SCALE*LOG2E so GEMM scores come out in log2 domain.
__global__ void k_prep(const float* __restrict__ v, const float* __restrict__ t,
                       unsigned short* __restrict__ Abf, unsigned short* __restrict__ Bbf,
                       float* __restrict__ thr, float* __restrict__ nom,
                       float* __restrict__ out) {
  const int tid = threadIdx.x, l = tid & 63, w = tid >> 6;
  const int i = blockIdx.x * 4 + w;            // one wave per video
  if (blockIdx.x == 0 && tid < 5) out[tid] = 0.0f;
  const float AS = SCALE * LOG2E;

  float4 a = ((const float4*)(v + (size_t)i * D_K))[l];
  ushort4 oa;
  oa.x = f2bf(a.x * AS); oa.y = f2bf(a.y * AS);
  oa.z = f2bf(a.z * AS); oa.w = f2bf(a.w * AS);
  ((ushort4*)(Abf + (size_t)i * D_K))[l] = oa;

  float tv[T_PER];
#pragma unroll
  for (int tt = 0; tt < T_PER; ++tt) {
    float4 b = ((const float4*)(t + (size_t)(i * T_PER + tt) * D_K))[l];
    ushort4 ob;
    ob.x = f2bf(b.x); ob.y = f2bf(b.y); ob.z = f2bf(b.z); ob.w = f2bf(b.w);
    ((ushort4*)(Bbf + (size_t)(i * T_PER + tt) * D_K))[l] = ob;
    float d = a.x * b.x + a.y * b.y + a.z * b.z + a.w * b.w;
#pragma unroll
    for (int s = 1; s < 64; s <<= 1) d += __shfl_xor(d, s);
    tv[tt] = d * SCALE;                        // natural-domain score
  }
  if (l == 0) {
    ((float4*)thr)[i] = make_float4(tv[0] * LOG2E, tv[1] * LOG2E,
                                    tv[2] * LOG2E, tv[3] * LOG2E);
    float m = fmaxf(fmaxf(tv[0], tv[1]), fmaxf(tv[2], tv[3]));
    float e = __expf(tv[0] - m) + __expf(tv[1] - m) + __expf(tv[2] - m) + __expf(tv[3] - m);
    nom[i] = m + __logf(e);
  }
}

// ---------------- B: barrier-free K-loop GEMM --------------------------------------------
// Block = 64 rows x 256 cols. A (64x256, 32 KB, full K) staged to LDS ONCE (single
// __syncthreads). B fragments stream directly from global/L2 (the B-operand layout is 16
// full 64B lines per global_load_dwordx4 — zero over-fetch; numerics verified in r5),
// double-buffered one 32-k chunk deep so the compiler emits fine-grained vmcnt(N), never a
// collective vmcnt(0) barrier drain. bid%8 == ct%8 -> each B slice is XCD-L2-resident.
__device__ __forceinline__ void gld16(const void* g, void* l) {
  __builtin_amdgcn_global_load_lds((const __attribute__((address_space(1))) void*)g,
                                   (__attribute__((address_space(3))) void*)l,
                                   16, 0, 0);
}

__global__ __launch_bounds__(256) void k_gemm(
    const unsigned short* __restrict__ Abf, const unsigned short* __restrict__ Bbf,
    const float* __restrict__ thr,
    float* __restrict__ pmax, float* __restrict__ psum, uint4* __restrict__ pcnt,
    float* __restrict__ cmax, float* __restrict__ csum) {
  __shared__ __align__(16) unsigned short As[64 * 256];   // 32 KB, swizzled full-K A tile
  __shared__ float4   thrS[64];
  __shared__ float    rowMw[4][64], rowEw[4][64];
  __shared__ uint32_t rowCw[4][64];

  const int ct = blockIdx.x, rt = blockIdx.y;
  const int row0 = rt * 64, col0 = ct * 256;
  const int tid = threadIdx.x;
  const int l = tid & 63, w = tid >> 6;
  const int quad = l >> 4, nl = l & 15;

  if (tid < 64) thrS[tid] = ((const float4*)thr)[row0 + tid];

  // ---- stage A once: 32 groups of 1024 B; group g = (rowset rs = g>>2, k-span ks = g&3).
  // Lane l = lr*8+lc writes 16B chunk (lc^lr) of row lr at slot l*16 (XOR swizzle keeps
  // both the wave-uniform gld16 placement AND conflict-free ds_read_b128 later).
  const int lr = l >> 3, lc7 = l & 7;
  const int sc = lc7 ^ lr;
#pragma unroll
  for (int it = 0; it < 8; ++it) {
    int g = w * 8 + it;
    int rs = g >> 2, ks = g & 3;
    const unsigned short* ga =
        Abf + (size_t)(row0 + rs * 8 + lr) * D_K + ks * 64 + sc * 8;
    gld16(ga, (char*)As + g * 1024);
  }

  f32x4 acc[4][4];
#pragma unroll
  for (int i = 0; i < 4; ++i)
#pragma unroll
    for (int j = 0; j < 4; ++j) acc[i][j] = {0.f, 0.f, 0.f, 0.f};

  // per-lane B pointers: col = col0 + w*64 + j*16 + nl, k = quad*8 (+ chunk offsets)
  const unsigned short* pB[4];
#pragma unroll
  for (int j = 0; j < 4; ++j)
    pB[j] = Bbf + (size_t)(col0 + w * 64 + j * 16 + nl) * D_K + quad * 8;

  __syncthreads();   // the ONLY barrier before the epilogue

  bf16x8 bv[2][4];
#pragma unroll
  for (int j = 0; j < 4; ++j) bv[0][j] = *(const bf16x8*)(pB[j]);

#pragma unroll
  for (int c = 0; c < 8; ++c) {                 // 8 chunks of K=32
    const int cur = c & 1;
    if (c < 7) {
#pragma unroll
      for (int j = 0; j < 4; ++j)
        bv[cur ^ 1][j] = *(const bf16x8*)(pB[j] + (c + 1) * 32);
    }
    bf16x8 af[4];
#pragma unroll
    for (int i = 0; i < 4; ++i) {
      int r = i * 16 + nl;
      int rb = r & 7;
      int grp = (r >> 3) * 4 + (c >> 1);
      int cc = ((((c & 1) << 2) | quad) ^ rb);
      af[i] = *(const bf16x8*)((const char*)As + grp * 1024 + (rb * 8 + cc) * 16);
    }
#pragma unroll
    for (int i = 0; i < 4; ++i)
#pragma unroll
      for (int j = 0; j < 4; ++j)
        acc[i][j] = __builtin_amdgcn_mfma_f32_16x16x32_bf16(af[i], bv[cur][j],
                                                            acc[i][j], 0, 0, 0);
  }

  // ================= epilogue (scores in log2 domain) =================
  // C/D layout: col = nl, row = quad*4 + reg. Per-row/per-col maxes mandatory
  // (shared max underflows exp2 -> log(0) downstream — r2/r3 bug).

  uint32_t cnt[4][4];
#pragma unroll
  for (int i = 0; i < 4; ++i)
#pragma unroll
    for (int r = 0; r < 4; ++r) {
      float4 th = thrS[i * 16 + quad * 4 + r];
      uint32_t c = 0;
#pragma unroll
      for (int j = 0; j < 4; ++j) {
        float s = acc[i][j][r];
        c += (uint32_t)(s > th.x);
        c += (uint32_t)(s > th.y) << 8;
        c += (uint32_t)(s > th.z) << 16;
        c += (uint32_t)(s > th.w) << 24;
      }
      cnt[i][r] = c;
    }

  // row partials (this wave's 64-col strip): per-row max, exp2-sum, count
#pragma unroll
  for (int i = 0; i < 4; ++i)
#pragma unroll
    for (int r = 0; r < 4; ++r) {
      float m = fmaxf(fmaxf(acc[i][0][r], acc[i][1][r]), fmaxf(acc[i][2][r], acc[i][3][r]));
#pragma unroll
      for (int d = 1; d < 16; d <<= 1) m = fmaxf(m, __shfl_xor(m, d));
      float e = EXP2F(acc[i][0][r] - m) + EXP2F(acc[i][1][r] - m)
              + EXP2F(acc[i][2][r] - m) + EXP2F(acc[i][3][r] - m);
      uint32_t c = cnt[i][r];
#pragma unroll
      for (int d = 1; d < 16; d <<= 1) { e += __shfl_xor(e, d); c += __shfl_xor(c, d); }
      if (nl == 0) {
        int row = i * 16 + quad * 4 + r;
        rowMw[w][row] = m; rowEw[w][row] = e; rowCw[w][row] = c;   // fields <= 64, no ovf
      }
    }

  // col partials: whole 64-row column lives in this wave -> direct global write
#pragma unroll
  for (int j = 0; j < 4; ++j) {
    float m = -3.0e38f;
#pragma unroll
    for (int i = 0; i < 4; ++i)
#pragma unroll
      for (int r = 0; r < 4; ++r) m = fmaxf(m, acc[i][j][r]);
    m = fmaxf(m, __shfl_xor(m, 16));
    m = fmaxf(m, __shfl_xor(m, 32));
    float e = 0.f;
#pragma unroll
    for (int i = 0; i < 4; ++i)
#pragma unroll
      for (int r = 0; r < 4; ++r) e += EXP2F(acc[i][j][r] - m);
    e += __shfl_xor(e, 16);
    e += __shfl_xor(e, 32);
    if (quad == 0) {
      int colg = col0 + w * 64 + j * 16 + nl;
      size_t gi = (size_t)rt * NT + colg;
      cmax[gi] = m; csum[gi] = e;
    }
  }
  __syncthreads();

  // combine the 4 col-strips per row; counts unpacked to 32-bit (4x64=256 would overflow 8b)
  if (tid < 64) {
    float M0 = rowMw[0][tid], M1 = rowMw[1][tid], M2 = rowMw[2][tid], M3 = rowMw[3][tid];
    float Mx = fmaxf(fmaxf(M0, M1), fmaxf(M2, M3));
    float Sx = rowEw[0][tid] * EXP2F(M0 - Mx) + rowEw[1][tid] * EXP2F(M1 - Mx)
             + rowEw[2][tid] * EXP2F(M2 - Mx) + rowEw[3][tid] * EXP2F(M3 - Mx);
    uint32_t c0 = 0, c1 = 0, c2 = 0, c3 = 0;
#pragma unroll
    for (int ww = 0; ww < 4; ++ww) {
      uint32_t cc = rowCw[ww][tid];
      c0 += cc & 0xffu; c1 += (cc >> 8) & 0xffu;
      c2 += (cc >> 16) & 0xffu; c3 += cc >> 24;
    }
    size_t gi = (size_t)ct * N_V + row0 + tid;
    pmax[gi] = Mx; psum[gi] = Sx; pcnt[gi] = make_uint4(c0, c1, c2, c3);
  }
}

// ---------------- C: fused row (64 partials) + col (64 partials) reductions ---------------
__global__ void k_red(const float* __restrict__ pmax, const float* __restrict__ psum,
                      const uint4* __restrict__ pcnt,
                      const float* __restrict__ cmax, const float* __restrict__ csum,
                      float* __restrict__ rowm, float* __restrict__ rows_,
                      uint4* __restrict__ rcnt,
                      float* __restrict__ colm, float* __restrict__ cols) {
  __shared__ float Lm[4][64], Ls[4][64];
  __shared__ uint4 Lc[4][64];
  __shared__ float Cm[2][128], Cs[2][128];
  const int bid = blockIdx.x, tid = threadIdx.x;
  if (bid < 64) {                      // rows: 64 blocks x 64 rows, 64 partials each
    int l = tid & 63, w = tid >> 6;
    int row = bid * 64 + l;
    float M = -3.0e38f, S = 0.f;
    uint32_t c0 = 0, c1 = 0, c2 = 0, c3 = 0;
    for (int k = 0; k < 16; ++k) {
      size_t idx = (size_t)(w * 16 + k) * N_V + row;
      float m = pmax[idx], s = psum[idx];
      uint4 cc = pcnt[idx];
      float nM = fmaxf(M, m);
      S = S * EXP2F(M - nM) + s * EXP2F(m - nM);
      M = nM;
      c0 += cc.x; c1 += cc.y; c2 += cc.z; c3 += cc.w;
    }
    Lm[w][l] = M; Ls[w][l] = S; Lc[w][l] = make_uint4(c0, c1, c2, c3);
    __syncthreads();
    if (tid < 64) {
      float Mx = Lm[0][tid], Sx = Ls[0][tid];
      uint4 C = Lc[0][tid];
#pragma unroll
      for (int ww = 1; ww < 4; ++ww) {
        float m = Lm[ww][tid], s = Ls[ww][tid];
        float nM = fmaxf(Mx, m);
        Sx = Sx * EXP2F(Mx - nM) + s * EXP2F(m - nM);
        Mx = nM;
        uint4 cc = Lc[ww][tid];
        C.x += cc.x; C.y += cc.y; C.z += cc.z; C.w += cc.w;
      }
      int r = bid * 64 + tid;
      rowm[r] = Mx; rows_[r] = Sx; rcnt[r] = C;
    }
  } else {                             // cols: 128 blocks x 128 cols, 64 partials each
    int cb = bid - 64;
    int c = tid & 127, h = tid >> 7;
    int col = cb * 128 + c;
    float M = -3.0e38f, S = 0.f;
    for (int k = 0; k < 32; ++k) {
      size_t idx = (size_t)(h * 32 + k) * NT + col;
      float m = cmax[idx], s = csum[idx];
      float nM = fmaxf(M, m);
      S = S * EXP2F(M - nM) + s * EXP2F(m - nM);
      M = nM;
    }
    Cm[h][c] = M; Cs[h][c] = S;
    __syncthreads();
    if (tid < 128) {
      float M0 = Cm[0][tid], S0 = Cs[0][tid];
      float M1 = Cm[1][tid], S1 = Cs[1][tid];
      float Mx = fmaxf(M0, M1);
      float Sx = S0 * EXP2F(M0 - Mx) + S1 * EXP2F(M1 - Mx);
      int cg = cb * 128 + tid;
      colm[cg] = Mx; cols[cg] = Sx;
    }
  }
}

// ---------------- D: combine per row, loss + metrics, atomic means -------------------------
__global__ void k_final(const float* __restrict__ rowm, const float* __restrict__ rows_,
                        const uint4* __restrict__ rcnt, const float* __restrict__ nom,
                        const float* __restrict__ colm, const float* __restrict__ cols,
                        float* __restrict__ out) {
  int row = blockIdx.x * 256 + threadIdx.x;
  float M = rowm[row], S = rows_[row];
  float cm0 = colm[row * 4 + 0], cm1 = colm[row * 4 + 1];
  float cm2 = colm[row * 4 + 2], cm3 = colm[row * 4 + 3];
  float cs0 = cols[row * 4 + 0], cs1 = cols[row * 4 + 1];
  float cs2 = cols[row * 4 + 2], cs3 = cols[row * 4 + 3];
  float Mp = fmaxf(M, fmaxf(fmaxf(cm0, cm1), fmaxf(cm2, cm3)));
  float tot = S * EXP2F(M - Mp)
            + cs0 * EXP2F(cm0 - Mp) + cs1 * EXP2F(cm1 - Mp)
            + cs2 * EXP2F(cm2 - Mp) + cs3 * EXP2F(cm3 - Mp);
  // scores in log2 domain: natural-log LSE = LN2 * (Mp + log2(tot))
  float ll = LN2 * (Mp + __log2f(tot)) - nom[row];
  uint4 c = rcnt[row];
  float ar  = (float)(c.x + c.y + c.z + c.w) * 0.25f;
  float r1  = (float)((c.x < 1u) + (c.y < 1u) + (c.z < 1u) + (c.w < 1u)) * 0.25f;
  float r5  = (float)((c.x < 5u) + (c.y < 5u) + (c.z < 5u) + (c.w < 5u)) * 0.25f;
  float r10 = (float)((c.x < 10u) + (c.y < 10u) + (c.z < 10u) + (c.w < 10u)) * 0.25f;
  float vals[5] = {ll, r1, r5, r10, ar};
  int l = threadIdx.x & 63;
#pragma unroll
  for (int k = 0; k < 5; ++k) {
    float v = vals[k];
#pragma unroll
    for (int d = 1; d < 64; d <<= 1) v += __shfl_xor(v, d);
    if (l == 0) atomicAdd(&out[k], v * (1.0f / N_V));
  }
}

extern "C" void kernel_launch(void* const* d_in, const int* in_sizes, int n_in,
                              void* d_out, int out_size, void* d_ws, size_t ws_size,
                              hipStream_t stream) {
  const float* v = (const float*)d_in[0];
  const float* t = (const float*)d_in[1];
  char* p = (char*)d_ws;
  unsigned short* Abf = (unsigned short*)p; p += (size_t)N_V * D_K * 2;
  unsigned short* Bbf = (unsigned short*)p; p += (size_t)NT * D_K * 2;
  float* thr  = (float*)p;    p += (size_t)N_V * 4 * 4;
  float* nom  = (float*)p;    p += (size_t)N_V * 4;
  float* pmax = (float*)p;    p += (size_t)64 * N_V * 4;
  float* psum = (float*)p;    p += (size_t)64 * N_V * 4;
  uint4* pcnt = (uint4*)p;    p += (size_t)64 * N_V * 16;
  float* cmaxp = (float*)p;   p += (size_t)64 * NT * 4;
  float* csump = (float*)p;   p += (size_t)64 * NT * 4;
  float* rowm = (float*)p;    p += (size_t)N_V * 4;
  float* rows_ = (float*)p;   p += (size_t)N_V * 4;
  uint4* rcnt = (uint4*)p;    p += (size_t)N_V * 16;
  float* colm = (float*)p;    p += (size_t)NT * 4;
  float* cols = (float*)p;    p += (size_t)NT * 4;
  // total ws: ~26 MB

  k_prep<<<N_V / 4, 256, 0, stream>>>(v, t, Abf, Bbf, thr, nom, (float*)d_out);
  dim3 g(NT / 256, N_V / 64);                     // ct x rt = 64 x 64
  k_gemm<<<g, 256, 0, stream>>>(Abf, Bbf, thr, pmax, psum, pcnt, cmaxp, csump);
  k_red<<<64 + NT / 128, 256, 0, stream>>>(pmax, psum, pcnt, cmaxp, csump,
                                           rowm, rows_, rcnt, colm, cols);
  k_final<<<N_V / 256, 256, 0, stream>>>(rowm, rows_, rcnt, nom, colm, cols, (float*)d_out);
}